// Round 14
// baseline (189.360 us; speedup 1.0000x reference)
//
#include <hip/hip_runtime.h>
#include <math.h>

#define BB 8
#define CC 64
#define OO 64
#define HH 128
#define WW 128
#define HW (HH*WW)              // 16384
#define NPIX (BB*HW)            // 131072

typedef __bf16 bf16x8 __attribute__((ext_vector_type(8)));
typedef float floatx4 __attribute__((ext_vector_type(4)));
typedef float f32x2 __attribute__((ext_vector_type(2)));
typedef unsigned short ushort_t;

// Workspace layout (bytes):
//  xt : bf16 NHWC [B][H][W][64]        16777216
//  om : fp32 [NPIX][28]                14680064
//  wt : bf16 [64][576]  (o, tap*64+c)     73728
//  wb : bf16 [32][576]  (o27pad, k)       36864
#define XT_BYTES  16777216
#define OM_BYTES  14680064
#define WT_BYTES  73728

__device__ __forceinline__ unsigned short f2b(float f) {
    unsigned u = __float_as_uint(f);
    u += 0x7fffu + ((u >> 16) & 1u);       // round-to-nearest-even
    return (unsigned short)(u >> 16);
}

// packed 2xf32 -> 2xbf16 in one VALU op (no builtin on gfx950; asm per guide)
__device__ __forceinline__ unsigned cvt_pk_bf16(float lo, float hi) {
    unsigned r;
    asm("v_cvt_pk_bf16_f32 %0, %1, %2" : "=v"(r) : "v"(lo), "v"(hi));
    return r;
}

__device__ __forceinline__ f32x2 pk_fma(f32x2 a, f32x2 b, f32x2 c) {
    f32x2 d;
    asm("v_pk_fma_f32 %0, %1, %2, %3" : "=v"(d) : "v"(a), "v"(b), "v"(c));
    return d;
}

__device__ __forceinline__ f32x2 pk_mul(f32x2 a, f32x2 b) {
    f32x2 d;
    asm("v_pk_mul_f32 %0, %1, %2" : "=v"(d) : "v"(a), "v"(b));
    return d;
}

// ---------------------------------------------------------------------------
// Kernel 1: FUSED prep — transpose (blocks 0..4095) + weight repack (4096..)
// Vectorized loads (2x float4) and stores (uint4 = 8 bf16 ch).
// ---------------------------------------------------------------------------
__global__ __launch_bounds__(256) void prep_kernel(
    const float* __restrict__ x,
    const float* __restrict__ wm, const float* __restrict__ woff,
    const float* __restrict__ wmask,
    ushort_t* __restrict__ xt, ushort_t* __restrict__ wt,
    ushort_t* __restrict__ wb)
{
    __shared__ float tile[64][33];
    int bid = blockIdx.x;
    int t   = threadIdx.x;

    if (bid < 4096) {
        // ---- transpose: NCHW fp32 -> NHWC bf16 ----
        int bh = bid >> 2;
        int w0 = (bid & 3) * 32;
        int b  = bh >> 7;
        int h  = bh & 127;

        {
            int c  = t >> 2;
            int wq = t & 3;
            const float* src = x + (((size_t)(b*CC + c))*HH + h)*WW + (w0 + wq*8);
            float4 v0 = ((const float4*)src)[0];
            float4 v1 = ((const float4*)src)[1];
            int wbse = wq*8;
            tile[c][wbse+0] = v0.x; tile[c][wbse+1] = v0.y;
            tile[c][wbse+2] = v0.z; tile[c][wbse+3] = v0.w;
            tile[c][wbse+4] = v1.x; tile[c][wbse+5] = v1.y;
            tile[c][wbse+6] = v1.z; tile[c][wbse+7] = v1.w;
        }
        __syncthreads();
        {
            int w   = t & 31;
            int cg8 = t >> 5;
            unsigned uu[4];
            #pragma unroll
            for (int j = 0; j < 4; ++j)
                uu[j] = cvt_pk_bf16(tile[cg8*8 + 2*j][w], tile[cg8*8 + 2*j + 1][w]);
            *(uint4*)(xt + (((size_t)(b*HH + h))*WW + (w0 + w))*CC + cg8*8)
                = make_uint4(uu[0], uu[1], uu[2], uu[3]);
        }
    } else {
        // ---- weight repack to bf16 ----
        int i = (bid - 4096) * 256 + t;
        if (i < 36864) {
            int o = i / 576, k = i % 576, tap = k >> 6, c = k & 63;
            wt[i] = f2b(wm[o*576 + c*9 + tap]);
        }
        int j = i - 36864;
        if (j >= 0 && j < 18432) {
            int o = j / 576, k = j % 576, tap = k >> 6, c = k & 63;
            float v = 0.f;
            if (o < 18)      v = woff[o*576 + c*9 + tap];
            else if (o < 27) v = wmask[(o-18)*576 + c*9 + tap];
            wb[j] = f2b(v);
        }
    }
}

// ---------------------------------------------------------------------------
// Kernel 2: conv3x3 -> 18 offsets + 9 sigmoid masks (r5 form, 16x16 tiles).
// ---------------------------------------------------------------------------
__global__ __launch_bounds__(256) void conv27_kernel(
    const ushort_t* __restrict__ xt, const ushort_t* __restrict__ wb,
    const float* __restrict__ boff, const float* __restrict__ bmsk,
    float* __restrict__ om)
{
    __shared__ ushort_t win[18*18*72];
    int bid = blockIdx.x;
    int b  = bid >> 6;
    int th = (bid >> 3) & 7;
    int tw = bid & 7;
    int h0 = th * 16, w0 = tw * 16;
    int t = threadIdx.x;

    for (int idx = t; idx < 18*18*8; idx += 256) {
        int r   = idx / 144;
        int rem = idx - r*144;
        int col = rem >> 3;
        int ch  = (rem & 7) << 3;
        int y = h0 + r - 1, x = w0 + col - 1;
        uint4 val = make_uint4(0,0,0,0);
        if ((unsigned)y < (unsigned)HH && (unsigned)x < (unsigned)WW)
            val = *(const uint4*)(xt + ((((size_t)b*HH + y)*WW + x) << 6) + ch);
        *(uint4*)(win + (r*18 + col)*72 + ch) = val;
    }
    __syncthreads();

    int lane = t & 63, wv = t >> 6;
    int n = lane & 15, quad = lane >> 4;
    const ushort_t* wb0 = wb + n*576;
    const ushort_t* wb1 = wb + (16 + n)*576;

    floatx4 acc0[4], acc1[4];
    #pragma unroll
    for (int mt = 0; mt < 4; ++mt) {
        acc0[mt] = (floatx4){0.f,0.f,0.f,0.f};
        acc1[mt] = (floatx4){0.f,0.f,0.f,0.f};
    }

    #pragma unroll
    for (int s = 0; s < 18; ++s) {
        int tap  = s >> 1;
        int tr   = tap / 3, tc = tap % 3;
        int coff = (s & 1)*32 + quad*8;
        int kk = tap*64 + coff;
        bf16x8 b0 = *(const bf16x8*)(wb0 + kk);
        bf16x8 b1 = *(const bf16x8*)(wb1 + kk);
        #pragma unroll
        for (int mt = 0; mt < 4; ++mt) {
            int ty = wv*4 + mt;
            bf16x8 a = *(const bf16x8*)(win + ((ty + tr)*18 + (n + tc))*72 + coff);
            acc0[mt] = __builtin_amdgcn_mfma_f32_16x16x32_bf16(a, b0, acc0[mt], 0, 0, 0);
            acc1[mt] = __builtin_amdgcn_mfma_f32_16x16x32_bf16(a, b1, acc1[mt], 0, 0, 0);
        }
    }

    #pragma unroll
    for (int mt = 0; mt < 4; ++mt) {
        int ty = wv*4 + mt;
        #pragma unroll
        for (int r = 0; r < 4; ++r) {
            int tx = quad*4 + r;
            size_t p = ((size_t)(b*HH + h0 + ty))*WW + (w0 + tx);
            float* dst = om + p*28;
            dst[n] = acc0[mt][r] + boff[n];
            int o1 = 16 + n;
            if (o1 < 18) {
                dst[o1] = acc1[mt][r] + boff[o1];
            } else if (o1 < 27) {
                float z = acc1[mt][r] + bmsk[o1 - 18];
                dst[o1] = 1.f / (1.f + expf(-z));
            } else if (o1 == 27) {
                dst[27] = 0.f;
            }
        }
    }
}

// ---------------------------------------------------------------------------
// Kernel 3: deform — BARRIER-FREE register-direct with LDS-halo gathers.
//
// 13 rounds of evidence: deform ~52-53us across 4 schedules, VALUBusy ~38%,
// MfmaUtil ~7% — latency-bound on the barrier-coupled gather convoy.
// r2 (barrier-free) failed for two separable reasons: scattered GLOBAL
// gathers (16 px per instr) and a same-wave ds_write->lgkmcnt(0)->ds_read
// round-trip. This kernel fixes both:
//  - 12x12x64 halo staged once in LDS, XOR-swizzled 16B chunks:
//    chunk j of cell c lives at (j ^ (c&7))*16 within the cell's 128B slot
//    -> uniform bank-group spread, 16B aligned. LDS = 18432 B.
//  - Each wave independently: 16 px (p = wv*16+n), ALL 64 outputs.
//    Per tap: 8 ds_read_b128 from halo (no coalescing constraint) ->
//    pack in regs -> 8 MFMAs. ZERO barriers after the one staging barrier.
//  - Wave-uniform fallback to global gathers if any nonzero-weight corner
//    leaves the halo (|offset|>~1.5; never for 0.05-scale offsets).
//  - launch_bounds(256,4) caps VGPR at 128 (4 waves/SIMD). WRITE_SIZE is
//    the spill detector.
// ---------------------------------------------------------------------------
__global__ __launch_bounds__(256, 4) void deform_kernel(
    const ushort_t* __restrict__ xt, const float* __restrict__ om,
    const ushort_t* __restrict__ wt, float* __restrict__ out)
{
    __shared__ ushort_t halo[144*64];    // 18432 B; cell = 128B, 8 swz chunks

    int t = threadIdx.x;
    int lane = t & 63, wv = t >> 6;
    int bid = blockIdx.x;
    int b  = bid >> 8;
    int th = (bid >> 4) & 15;
    int tw = bid & 15;
    int h0 = th * 8, w0 = tw * 8;

    const ushort_t* xbase = xt + ((size_t)b << 20);
    int n = lane & 15, quad = lane >> 4;

    // ---------------- stage 12x12 halo, swizzled ----------------
    for (int idx = t; idx < 1152; idx += 256) {
        int cell = idx >> 3;             // 0..143
        int jj   = idx & 7;              // 16B chunk (8 ch)
        int cy = cell / 12, cx = cell - cy*12;
        int y = h0 + cy - 2, xx = w0 + cx - 2;
        uint4 val = make_uint4(0,0,0,0);
        if ((unsigned)y < (unsigned)HH && (unsigned)xx < (unsigned)WW)
            val = *(const uint4*)(xbase + (((y << 7) + xx) << 6) + jj*8);
        *(uint4*)(halo + cell*64 + ((jj ^ (cell & 7)) << 3)) = val;
    }
    __syncthreads();   // the ONLY barrier

    // this lane's pixel (16 px per wave) and channel slice (quad)
    int p_lin = wv*16 + n;
    int h_a = h0 + (p_lin >> 3), w_a = w0 + (p_lin & 7);
    const float* omp = om + (((size_t)(b*HH + h_a))*WW + w_a) * 28;
    const ushort_t* wrow = wt + n*576 + quad*8;

    floatx4 acc[4];
    #pragma unroll
    for (int i = 0; i < 4; ++i) acc[i] = (floatx4){0.f,0.f,0.f,0.f};

    float dy = omp[0], dx = omp[1], m = omp[18];

    #pragma unroll
    for (int g = 0; g < 9; ++g) {
        int kr = g / 3, kc = g - kr*3;   // compile-time after unroll

        // prefetch next tap's params
        float dy_n = 0.f, dx_n = 0.f, m_n = 0.f;
        if (g < 8) { dy_n = omp[2*g + 2]; dx_n = omp[2*g + 3]; m_n = omp[19 + g]; }

        // prefetch this tap's 8 B-frags (L1/L2-hot 73KB table)
        bf16x8 wf[8];
        #pragma unroll
        for (int og = 0; og < 4; ++og) {
            wf[og*2]   = *(const bf16x8*)(wrow + og*(16*576) + g*64);
            wf[og*2+1] = *(const bf16x8*)(wrow + og*(16*576) + g*64 + 32);
        }

        // bilinear setup (4 lanes/px redundant — broadcast om reads)
        float py = (float)(h_a + kr - 1) + dy;
        float px = (float)(w_a + kc - 1) + dx;
        float y0f = floorf(py), x0f = floorf(px);
        float ly = py - y0f, lx = px - x0f;
        int y0 = (int)y0f, x0 = (int)x0f, y1 = y0 + 1, x1 = x0 + 1;
        float vy0 = ((unsigned)y0 < (unsigned)HH) ? 1.f : 0.f;
        float vy1 = ((unsigned)y1 < (unsigned)HH) ? 1.f : 0.f;
        float vx0 = ((unsigned)x0 < (unsigned)WW) ? 1.f : 0.f;
        float vx1 = ((unsigned)x1 < (unsigned)WW) ? 1.f : 0.f;

        float cw[4] = { (1.f-ly)*(1.f-lx)*vy0*vx0*m,
                        (1.f-ly)*lx      *vy0*vx1*m,
                        ly*(1.f-lx)      *vy1*vx0*m,
                        ly*lx            *vy1*vx1*m };
        int ys[4] = { y0, y0, y1, y1 };
        int xs[4] = { x0, x1, x0, x1 };

        dy = dy_n; dx = dx_n; m = m_n;

        // clamp + halo residency test (wave-uniform path select)
        int ycl[4], xcl[4], cells[4];
        int ok = 1;
        #pragma unroll
        for (int cn = 0; cn < 4; ++cn) {
            int yc = min(max(ys[cn], 0), HH-1);
            int xc = min(max(xs[cn], 0), WW-1);
            ycl[cn] = yc; xcl[cn] = xc;
            int hy = yc - h0 + 2, hx = xc - w0 + 2;
            int inh = ((unsigned)hy < 12u) & ((unsigned)hx < 12u);
            ok &= ((cw[cn] == 0.f) | inh);
            cells[cn] = min(max(hy, 0), 11)*12 + min(max(hx, 0), 11);
        }

        uint4 qd[8];
        if (__all(ok)) {
            // fast path: swizzled LDS halo reads (2x b128/corner)
            #pragma unroll
            for (int cn = 0; cn < 4; ++cn) {
                int c = cells[cn];
                const ushort_t* cb = halo + c*64;
                qd[2*cn]   = *(const uint4*)(cb + ((quad       ^ (c & 7)) << 3));
                qd[2*cn+1] = *(const uint4*)(cb + (((quad + 4) ^ (c & 7)) << 3));
            }
        } else {
            // fallback: global gathers (correct for any offset)
            #pragma unroll
            for (int cn = 0; cn < 4; ++cn) {
                const uint4* cp = (const uint4*)(xbase
                    + (((ycl[cn] << 7) + xcl[cn]) << 6) + quad*8);
                qd[2*cn]   = cp[0];
                qd[2*cn+1] = cp[4];      // +32 ch
            }
        }

        // packed fp32 corner accumulate: v2[0..3]=lo 8ch, v2[4..7]=hi 8ch
        f32x2 v2[8];
        {
            f32x2 w2; w2.x = cw[0]; w2.y = cw[0];
            unsigned u0[8] = { qd[0].x, qd[0].y, qd[0].z, qd[0].w,
                               qd[1].x, qd[1].y, qd[1].z, qd[1].w };
            #pragma unroll
            for (int j = 0; j < 8; ++j) {
                f32x2 f;
                f.x = __uint_as_float(u0[j] << 16);
                f.y = __uint_as_float(u0[j] & 0xffff0000u);
                v2[j] = pk_mul(f, w2);
            }
        }
        #pragma unroll
        for (int cn = 1; cn < 4; ++cn) {
            f32x2 w2; w2.x = cw[cn]; w2.y = cw[cn];
            unsigned u0[8] = { qd[2*cn].x,   qd[2*cn].y,
                               qd[2*cn].z,   qd[2*cn].w,
                               qd[2*cn+1].x, qd[2*cn+1].y,
                               qd[2*cn+1].z, qd[2*cn+1].w };
            #pragma unroll
            for (int j = 0; j < 8; ++j) {
                f32x2 f;
                f.x = __uint_as_float(u0[j] << 16);
                f.y = __uint_as_float(u0[j] & 0xffff0000u);
                v2[j] = pk_fma(f, w2, v2[j]);
            }
        }

        // A-fragments in registers: a0 = ch quad*8.., a1 = ch 32+quad*8..
        union { uint4 u; bf16x8 v; } a0, a1;
        a0.u = make_uint4(cvt_pk_bf16(v2[0].x, v2[0].y),
                          cvt_pk_bf16(v2[1].x, v2[1].y),
                          cvt_pk_bf16(v2[2].x, v2[2].y),
                          cvt_pk_bf16(v2[3].x, v2[3].y));
        a1.u = make_uint4(cvt_pk_bf16(v2[4].x, v2[4].y),
                          cvt_pk_bf16(v2[5].x, v2[5].y),
                          cvt_pk_bf16(v2[6].x, v2[6].y),
                          cvt_pk_bf16(v2[7].x, v2[7].y));

        // 8 MFMAs (all 64 outputs), no barrier
        __builtin_amdgcn_s_setprio(1);
        #pragma unroll
        for (int og = 0; og < 4; ++og)
            acc[og] = __builtin_amdgcn_mfma_f32_16x16x32_bf16(a0.v, wf[og*2],   acc[og], 0, 0, 0);
        #pragma unroll
        for (int og = 0; og < 4; ++og)
            acc[og] = __builtin_amdgcn_mfma_f32_16x16x32_bf16(a1.v, wf[og*2+1], acc[og], 0, 0, 0);
        __builtin_amdgcn_s_setprio(0);
    }

    // store: out[b][o][h][w], o = og*16 + n; D row = wave-local pixel
    // px_local = quad*4 + r -> row = h0 + wv*2 + (quad>>1),
    //                          col = w0 + (quad&1)*4 + r   (verified r2/r3)
    int row = h0 + wv*2 + (quad >> 1);
    int col = w0 + (quad & 1)*4;
    #pragma unroll
    for (int og = 0; og < 4; ++og) {
        float* op = out + ((size_t)b*OO + (og*16 + n))*HW;
        float4 st = make_float4(acc[og][0], acc[og][1], acc[og][2], acc[og][3]);
        *(float4*)(op + row*WW + col) = st;
    }
}

// ---------------------------------------------------------------------------
extern "C" void kernel_launch(void* const* d_in, const int* in_sizes, int n_in,
                              void* d_out, int out_size, void* d_ws, size_t ws_size,
                              hipStream_t stream)
{
    const float* x      = (const float*)d_in[0];
    const float* w_main = (const float*)d_in[1];
    const float* w_off  = (const float*)d_in[2];
    const float* b_off  = (const float*)d_in[3];
    const float* w_msk  = (const float*)d_in[4];
    const float* b_msk  = (const float*)d_in[5];
    float* out = (float*)d_out;

    unsigned char* ws = (unsigned char*)d_ws;
    ushort_t* xt = (ushort_t*)ws;
    float*    om = (float*)(ws + XT_BYTES);
    ushort_t* wt = (ushort_t*)(ws + XT_BYTES + OM_BYTES);
    ushort_t* wb = (ushort_t*)(ws + XT_BYTES + OM_BYTES + WT_BYTES);

    // K1: transpose (4096 blocks) + repack (216 blocks) fused
    prep_kernel<<<4096 + 216, 256, 0, stream>>>(x, w_main, w_off, w_msk, xt, wt, wb);

    // K2: conv27 (r5 form)
    conv27_kernel<<<NPIX/256, 256, 0, stream>>>(xt, wb, b_off, b_msk, om);

    // K3: deform, barrier-free register-direct + swizzled LDS halo
    deform_kernel<<<NPIX/64, 256, 0, stream>>>(xt, om, wt, out);
}